// Round 3
// baseline (89.682 us; speedup 1.0000x reference)
//
#include <hip/hip_runtime.h>

// N-body all-pairs gravitational force, N=8192, fp32.
//
// Round-10: kill the transcendental. r7/r8/r9 data: nbody time (~37us) is
// invariant to waves/SIMD (2 vs 4), chains (8 vs 16), and wave-k-iter count
// (256 vs 512 per SIMD) -- only per-SIMD pair-work is invariant => a
// THROUGHPUT bound at ~87 cyc per wave-pair. VALU execution is only 24 cyc
// of that; the only other per-pair op is v_rsq_f32. Hypothesis: gfx950
// wave64 rsq occupies the SIMD ~64+ cyc (slow trans pipe blocks issue).
// Fix: integer-hack rsqrt + 3 Newton iterations = 12 pure-VALU insts,
// ~1-2ulp accurate (e3 ~ 3e-11 < fp32 eps).
//  - config identical to r8 (BLOCK=256, IBLK=2, JSPLIT=64, 6.3MB partials)
//    -> clean single-variable A/B on the rsq replacement.
// Prediction: nbody ~37 -> ~20-22us, dur_us 80 -> ~64-67, absmax ~0.1-0.3.
// If dur unchanged ~80: neither VALU nor trans binds -> disasm next.

constexpr int   NBODY   = 8192;
constexpr int   BLOCK   = 256;
constexpr int   IBLK    = 2;
constexpr int   IBODIES = BLOCK * IBLK;        // 512 i's per block
constexpr int   JSPLIT  = 64;
constexpr int   JPER    = NBODY / JSPLIT;      // 128 j's per block
constexpr float SOFT2   = 0.01f * 0.01f;
constexpr int   OUTE    = NBODY * 3;           // 24576

__device__ __forceinline__ float fast_rsqrt(float x) {
    // Quake-style seed + 3 NR iterations: converges to ~1-2 ulp for
    // normal positive x (d2 >= SOFT2 = 1e-4 here, always normal).
    float y = __uint_as_float(0x5f3759dfu - (__float_as_uint(x) >> 1));
    const float hx = 0.5f * x;
    y = y * fmaf(-hx * y, y, 1.5f);
    y = y * fmaf(-hx * y, y, 1.5f);
    y = y * fmaf(-hx * y, y, 1.5f);
    return y;
}

__global__ __launch_bounds__(BLOCK, 4) void nbody_forces(
    const float* __restrict__ pos,       // [N,3]
    const float* __restrict__ mass,      // [N]
    float*       __restrict__ part)      // [JSPLIT][N*3] partials
{
    const int tid   = threadIdx.x;
    const int iBase = blockIdx.x * IBODIES + tid;
    const int j0    = blockIdx.y * JPER;

    __shared__ float4 sh[JPER];
    if (tid < JPER) {                    // JPER=128 < BLOCK=256: half stage
        const int j = j0 + tid;
        sh[tid] = make_float4(pos[3 * j + 0], pos[3 * j + 1], pos[3 * j + 2], mass[j]);
    }

    float px[IBLK], py[IBLK], pz[IBLK];
    #pragma unroll
    for (int b = 0; b < IBLK; ++b) {
        const int i = iBase + b * BLOCK;
        px[b] = pos[3 * i + 0];
        py[b] = pos[3 * i + 1];
        pz[b] = pos[3 * i + 2];
    }
    __syncthreads();

    float fx[IBLK], fy[IBLK], fz[IBLK];
    #pragma unroll
    for (int b = 0; b < IBLK; ++b) { fx[b] = 0.f; fy[b] = 0.f; fz[b] = 0.f; }

    #pragma unroll 8
    for (int k = 0; k < JPER; ++k) {
        const float4 p = sh[k];            // uniform addr -> HW broadcast
        #pragma unroll
        for (int b = 0; b < IBLK; ++b) {
            const float dx = p.x - px[b];
            const float dy = p.y - py[b];
            const float dz = p.z - pz[b];
            const float d2 = fmaf(dx, dx, fmaf(dy, dy, fmaf(dz, dz, SOFT2)));
            const float inv = fast_rsqrt(d2);               // pure VALU
            const float s   = p.w * inv * inv * inv;        // G = 1
            fx[b] = fmaf(s, dx, fx[b]);
            fy[b] = fmaf(s, dy, fy[b]);
            fz[b] = fmaf(s, dz, fz[b]);
            // j == i: diff = 0 -> contribution 0, matches reference.
        }
    }

    float* dst = part + (size_t)blockIdx.y * OUTE;
    #pragma unroll
    for (int b = 0; b < IBLK; ++b) {
        const int i = iBase + b * BLOCK;
        dst[3 * i + 0] = fx[b];
        dst[3 * i + 1] = fy[b];
        dst[3 * i + 2] = fz[b];
    }
}

__global__ __launch_bounds__(256) void reduce_kernel(
    const float* __restrict__ part,      // [JSPLIT][OUTE]
    float*       __restrict__ out)       // [OUTE]
{
    const int e = blockIdx.x * blockDim.x + threadIdx.x;   // 0..OUTE-1
    float s = 0.f;
    #pragma unroll 8
    for (int k = 0; k < JSPLIT; ++k)
        s += part[(size_t)k * OUTE + e];
    out[e] = s;
}

extern "C" void kernel_launch(void* const* d_in, const int* in_sizes, int n_in,
                              void* d_out, int out_size, void* d_ws, size_t ws_size,
                              hipStream_t stream) {
    const float* pos  = (const float*)d_in[0];
    const float* mass = (const float*)d_in[1];
    float* out = (float*)d_out;

    float* part = (float*)d_ws;          // [JSPLIT][OUTE] = 6.3 MB

    dim3 grid(NBODY / IBODIES, JSPLIT);  // (16, 64) = 1024 blocks
    nbody_forces<<<grid, BLOCK, 0, stream>>>(pos, mass, part);

    reduce_kernel<<<OUTE / 256, 256, 0, stream>>>(part, out);
}

// Round 4
// 79.495 us; speedup vs baseline: 1.1281x; 1.1281x over previous
//
#include <hip/hip_runtime.h>

// N-body all-pairs gravitational force, N=8192, fp32.
//
// Round-11: software-pipeline the LDS read. Calibration from r10: marginal
// VALU costs 2 cyc/inst at full clock (+12 insts/pair == +9.7us exactly),
// rsq is ~free, so r8's 173 cyc/wave-k-iter = 52 VALU + ~16 ovh + ~105
// UNHIDDEN ds_read latency (~120 cyc): compiler emits ds_read->waitcnt->use
// per iter, no batching, and lockstep-ish waves don't cover each other.
// Fix: manual prefetch rotation -- load sh[k+1] into regs while computing
// on sh[k]; the ds_read gets a whole iteration of VALU to complete.
//  - config identical to r8 otherwise (BLOCK=256, IBLK=2, JSPLIT=64,
//    v_rsq_f32 restored) -> single-variable A/B on the prefetch.
// Prediction: nbody ~37 -> ~16-20us, dur_us 80 -> ~58-64, absmax 0.125.
// If unchanged: LDS-latency theory dead -> s_load/uniform-global next.

constexpr int   NBODY   = 8192;
constexpr int   BLOCK   = 256;
constexpr int   IBLK    = 2;
constexpr int   IBODIES = BLOCK * IBLK;        // 512 i's per block
constexpr int   JSPLIT  = 64;
constexpr int   JPER    = NBODY / JSPLIT;      // 128 j's per block
constexpr float SOFT2   = 0.01f * 0.01f;
constexpr int   OUTE    = NBODY * 3;           // 24576

__global__ __launch_bounds__(BLOCK, 4) void nbody_forces(
    const float* __restrict__ pos,       // [N,3]
    const float* __restrict__ mass,      // [N]
    float*       __restrict__ part)      // [JSPLIT][N*3] partials
{
    const int tid   = threadIdx.x;
    const int iBase = blockIdx.x * IBODIES + tid;
    const int j0    = blockIdx.y * JPER;

    __shared__ float4 sh[JPER + 1];      // +1 pad: prefetch overruns by one
    if (tid < JPER) {                    // JPER=128 < BLOCK=256: half stage
        const int j = j0 + tid;
        sh[tid] = make_float4(pos[3 * j + 0], pos[3 * j + 1], pos[3 * j + 2], mass[j]);
    }
    if (tid == JPER) sh[JPER] = make_float4(0.f, 0.f, 0.f, 0.f);

    float px[IBLK], py[IBLK], pz[IBLK];
    #pragma unroll
    for (int b = 0; b < IBLK; ++b) {
        const int i = iBase + b * BLOCK;
        px[b] = pos[3 * i + 0];
        py[b] = pos[3 * i + 1];
        pz[b] = pos[3 * i + 2];
    }
    __syncthreads();

    float fx[IBLK], fy[IBLK], fz[IBLK];
    #pragma unroll
    for (int b = 0; b < IBLK; ++b) { fx[b] = 0.f; fy[b] = 0.f; fz[b] = 0.f; }

    float4 pnext = sh[0];                // prime the pipeline
    #pragma unroll 8
    for (int k = 0; k < JPER; ++k) {
        const float4 p = pnext;          // value loaded one iter ago
        pnext = sh[k + 1];               // issue next ds_read now; waitcnt
                                         // lands after this iter's VALU
        #pragma unroll
        for (int b = 0; b < IBLK; ++b) {
            const float dx = p.x - px[b];
            const float dy = p.y - py[b];
            const float dz = p.z - pz[b];
            const float d2 = fmaf(dx, dx, fmaf(dy, dy, fmaf(dz, dz, SOFT2)));
            const float inv = __builtin_amdgcn_rsqf(d2);    // v_rsq_f32 (free, r10)
            const float s   = p.w * inv * inv * inv;        // G = 1
            fx[b] = fmaf(s, dx, fx[b]);
            fy[b] = fmaf(s, dy, fy[b]);
            fz[b] = fmaf(s, dz, fz[b]);
            // j == i: diff = 0 -> contribution 0, matches reference.
        }
    }

    float* dst = part + (size_t)blockIdx.y * OUTE;
    #pragma unroll
    for (int b = 0; b < IBLK; ++b) {
        const int i = iBase + b * BLOCK;
        dst[3 * i + 0] = fx[b];
        dst[3 * i + 1] = fy[b];
        dst[3 * i + 2] = fz[b];
    }
}

__global__ __launch_bounds__(256) void reduce_kernel(
    const float* __restrict__ part,      // [JSPLIT][OUTE]
    float*       __restrict__ out)       // [OUTE]
{
    const int e = blockIdx.x * blockDim.x + threadIdx.x;   // 0..OUTE-1
    float s = 0.f;
    #pragma unroll 8
    for (int k = 0; k < JSPLIT; ++k)
        s += part[(size_t)k * OUTE + e];
    out[e] = s;
}

extern "C" void kernel_launch(void* const* d_in, const int* in_sizes, int n_in,
                              void* d_out, int out_size, void* d_ws, size_t ws_size,
                              hipStream_t stream) {
    const float* pos  = (const float*)d_in[0];
    const float* mass = (const float*)d_in[1];
    float* out = (float*)d_out;

    float* part = (float*)d_ws;          // [JSPLIT][OUTE] = 6.3 MB

    dim3 grid(NBODY / IBODIES, JSPLIT);  // (16, 64) = 1024 blocks
    nbody_forces<<<grid, BLOCK, 0, stream>>>(pos, mass, part);

    reduce_kernel<<<OUTE / 256, 256, 0, stream>>>(part, out);
}

// Round 6
// 76.772 us; speedup vs baseline: 1.1682x; 1.0355x over previous
//
#include <hip/hip_runtime.h>

// N-body all-pairs gravitational force, N=8192, fp32.
//
// Round-13: packed fp32, take 2 -- via compiler, not blind asm. r12's
// hand-written v_pk_* inline asm produced absmax 2e5 (j-data/softening
// scrambled => asm mechanics wrong; logic audit clean). LLVM ISel forms
// v_pk_{add,mul,fma}_f32 from <2 x float> ops on gfx90a+, with correct
// register pairing/modifiers. So: ext-vector math + __builtin_elementwise_fma.
// Graceful degradation: if ISel scalarizes, codegen == r8 (neutral, correct).
// Model (fit r7-r11): nbody VALU-issue-bound, 26 insts/k-iter -> 11.1us;
// packed j-pairs cut to ~16 insts/2 pairs.
//  - structure identical to r12: BLOCK=256, IBLK=2, JSPLIT=64, SoA LDS,
//    4 waves/SIMD, pre-negated i-coords so dx = xj + (-xi) is pk_add.
// Prediction: packed -> nbody ~7.5, dur ~75-77; scalarized -> ~80 neutral.
// absmax ~0.125 either way.

constexpr int   NBODY   = 8192;
constexpr int   BLOCK   = 256;
constexpr int   IBLK    = 2;
constexpr int   IBODIES = BLOCK * IBLK;        // 512 i's per block
constexpr int   JSPLIT  = 64;
constexpr int   JPER    = NBODY / JSPLIT;      // 128 j's per block
constexpr float SOFT2   = 0.01f * 0.01f;
constexpr int   OUTE    = NBODY * 3;           // 24576

typedef float v2f __attribute__((ext_vector_type(2)));

__global__ __launch_bounds__(BLOCK, 4) void nbody_forces(
    const float* __restrict__ pos,       // [N,3]
    const float* __restrict__ mass,      // [N]
    float*       __restrict__ part)      // [JSPLIT][N*3] partials
{
    const int tid   = threadIdx.x;
    const int iBase = blockIdx.x * IBODIES + tid;
    const int j0    = blockIdx.y * JPER;

    // SoA LDS tile: uniform-address b64 reads give {v_j0, v_j1} pairs.
    __shared__ float shx[JPER], shy[JPER], shz[JPER], shm[JPER];
    if (tid < JPER) {
        const int j = j0 + tid;
        shx[tid] = pos[3 * j + 0];
        shy[tid] = pos[3 * j + 1];
        shz[tid] = pos[3 * j + 2];
        shm[tid] = mass[j];
    }

    // Pre-negated i-coords, broadcast into both lanes: dx = xj + (-xi).
    v2f mpx[IBLK], mpy[IBLK], mpz[IBLK];
    #pragma unroll
    for (int b = 0; b < IBLK; ++b) {
        const int i = iBase + b * BLOCK;
        const float x = pos[3 * i + 0], y = pos[3 * i + 1], z = pos[3 * i + 2];
        mpx[b] = (v2f){-x, -x};
        mpy[b] = (v2f){-y, -y};
        mpz[b] = (v2f){-z, -z};
    }
    const v2f soft2_2 = (v2f){SOFT2, SOFT2};
    __syncthreads();

    v2f fx[IBLK], fy[IBLK], fz[IBLK];
    #pragma unroll
    for (int b = 0; b < IBLK; ++b) {
        fx[b] = (v2f){0.f, 0.f}; fy[b] = (v2f){0.f, 0.f}; fz[b] = (v2f){0.f, 0.f};
    }

    #pragma unroll 4
    for (int kk = 0; kk < JPER / 2; ++kk) {
        const v2f x2 = *reinterpret_cast<const v2f*>(&shx[2 * kk]);
        const v2f y2 = *reinterpret_cast<const v2f*>(&shy[2 * kk]);
        const v2f z2 = *reinterpret_cast<const v2f*>(&shz[2 * kk]);
        const v2f m2 = *reinterpret_cast<const v2f*>(&shm[2 * kk]);
        #pragma unroll
        for (int b = 0; b < IBLK; ++b) {
            const v2f dx = x2 + mpx[b];
            const v2f dy = y2 + mpy[b];
            const v2f dz = z2 + mpz[b];
            const v2f d2 = __builtin_elementwise_fma(dx, dx,
                           __builtin_elementwise_fma(dy, dy,
                           __builtin_elementwise_fma(dz, dz, soft2_2)));
            v2f inv;
            inv.x = __builtin_amdgcn_rsqf(d2.x);    // v_rsq_f32 (~free, r10)
            inv.y = __builtin_amdgcn_rsqf(d2.y);
            const v2f s = (m2 * inv) * (inv * inv); // m * inv^3  (G = 1)
            fx[b] = __builtin_elementwise_fma(s, dx, fx[b]);
            fy[b] = __builtin_elementwise_fma(s, dy, fy[b]);
            fz[b] = __builtin_elementwise_fma(s, dz, fz[b]);
            // j == i: diff = 0 -> contribution 0, matches reference.
        }
    }

    float* dst = part + (size_t)blockIdx.y * OUTE;
    #pragma unroll
    for (int b = 0; b < IBLK; ++b) {
        const int i = iBase + b * BLOCK;
        dst[3 * i + 0] = fx[b].x + fx[b].y;
        dst[3 * i + 1] = fy[b].x + fy[b].y;
        dst[3 * i + 2] = fz[b].x + fz[b].y;
    }
}

__global__ __launch_bounds__(256) void reduce_kernel(
    const float* __restrict__ part,      // [JSPLIT][OUTE]
    float*       __restrict__ out)       // [OUTE]
{
    const int e = blockIdx.x * blockDim.x + threadIdx.x;   // 0..OUTE-1
    float s = 0.f;
    #pragma unroll 8
    for (int k = 0; k < JSPLIT; ++k)
        s += part[(size_t)k * OUTE + e];
    out[e] = s;
}

extern "C" void kernel_launch(void* const* d_in, const int* in_sizes, int n_in,
                              void* d_out, int out_size, void* d_ws, size_t ws_size,
                              hipStream_t stream) {
    const float* pos  = (const float*)d_in[0];
    const float* mass = (const float*)d_in[1];
    float* out = (float*)d_out;

    float* part = (float*)d_ws;          // [JSPLIT][OUTE] = 6.3 MB

    dim3 grid(NBODY / IBODIES, JSPLIT);  // (16, 64) = 1024 blocks
    nbody_forces<<<grid, BLOCK, 0, stream>>>(pos, mass, part);

    reduce_kernel<<<OUTE / 256, 256, 0, stream>>>(part, out);
}